// Round 1
// baseline (502.944 us; speedup 1.0000x reference)
//
#include <hip/hip_runtime.h>
#include <hip/hip_bf16.h>
#include <math.h>

// Problem constants (BilinearGate): B=8, Cin=256, H=W=96 -> HW=9216, R=32,
// TRI = R*(R+1)/2 = 528, Cout=256.
#define HW    9216
#define CIN   256
#define RCH   32
#define NTRI  528
#define COUT  256
#define NB    8

// ---------------------------------------------------------------------------
// Kernel 1: reduce  out[b][r][p] = sum_c x[b][c][p] * w_reduce[r][c]
// One thread per pixel. x reads coalesced across lanes (p contiguous).
// w_reduce is wave-uniform -> compiler emits scalar loads (s_load) + v_fma
// with SGPR operand, so no LDS broadcast cost.
// ---------------------------------------------------------------------------
__global__ __launch_bounds__(256) void reduce_kernel(
    const float* __restrict__ x, const float* __restrict__ w_reduce,
    float* __restrict__ out) {
  int pp = blockIdx.x * 256 + threadIdx.x;   // 73728 total, exact
  int b = pp / HW;
  int p = pp - b * HW;
  const float* xb = x + (size_t)b * CIN * HW + p;
  float acc[RCH];
#pragma unroll
  for (int r = 0; r < RCH; ++r) acc[r] = 0.0f;
#pragma unroll 4
  for (int c = 0; c < CIN; ++c) {
    float xv = xb[(size_t)c * HW];
#pragma unroll
    for (int r = 0; r < RCH; ++r) acc[r] += xv * w_reduce[r * CIN + c];
  }
  float* ob = out + (size_t)b * RCH * HW + p;
#pragma unroll
  for (int r = 0; r < RCH; ++r) ob[(size_t)r * HW] = acc[r];
}

// ---------------------------------------------------------------------------
// Kernel 2: recover. Per block: 64 output channels x 64 pixels, K=528 in 33
// chunks of 16. outS (32x64) staged once; per chunk stage wS[16][68]
// (transposed w_recover) and compute upS[16][68] from outS on the fly.
// Thread (px=tid%16, oy=tid/16) owns a 4x4 register tile:
//   acc[a][bb] = y[o0+oy*4+a][p0+px*4+bb]
// Inner k-step: 2x ds_read_b128 + 16x v_fma_f32.
// Epilogue: signed sqrt, coalesced float4 stores.
// ---------------------------------------------------------------------------
__global__ __launch_bounds__(256) void recover_kernel(
    const float* __restrict__ out, const float* __restrict__ w_recover,
    float* __restrict__ y) {
  __shared__ float outS[RCH][64];
  __shared__ float upS[16][68];
  __shared__ float wS[16][68];
  __shared__ short triI[NTRI];
  __shared__ short triJ[NTRI];

  const int tid = threadIdx.x;
  const int bx = blockIdx.x;            // 4608 blocks
  const int ot = bx & 3;                // 4 o-tiles
  const int pt = bx >> 2;               // 1152 pixel tiles (144 per batch)
  const int b = pt / 144;
  const int p0 = (pt - b * 144) * 64;
  const int o0 = ot * 64;

  // Build triu index tables (closed-form inverse + integer fixup).
  for (int t = tid; t < NTRI; t += 256) {
    float disc = 4225.0f - 8.0f * (float)t;     // (65-2i)^2 at t=base(i)
    int i = (int)floorf((65.0f - sqrtf(disc)) * 0.5f);
    while ((i + 1) * (65 - (i + 1)) / 2 <= t) ++i;
    while (i * (65 - i) / 2 > t) --i;
    triI[t] = (short)i;
    triJ[t] = (short)(i + t - i * (65 - i) / 2);
  }

  // Stage out tile: outS[r][pl]
  {
    const float* ob = out + (size_t)b * RCH * HW + p0;
    for (int idx = tid; idx < RCH * 64; idx += 256) {
      int r = idx >> 6;
      int pl = idx & 63;
      outS[r][pl] = ob[(size_t)r * HW + pl];
    }
  }
  __syncthreads();

  const int px = tid & 15;   // pixel quad: pl = px*4 .. px*4+3
  const int oy = tid >> 4;   // o quad:     ol = oy*4 .. oy*4+3
  float acc[4][4];
#pragma unroll
  for (int a = 0; a < 4; ++a)
#pragma unroll
    for (int bb = 0; bb < 4; ++bb) acc[a][bb] = 0.0f;

  const int o_l = tid >> 2;  // 0..63, for w staging
  const int q   = tid & 3;   // 0..3

  for (int chunk = 0; chunk < 33; ++chunk) {
    const int t0 = chunk * 16;
    // Stage w chunk transposed: wS[t_l][o_l] = w_recover[o0+o_l][t0+t_l]
    {
      const float* wrow = w_recover + (size_t)(o0 + o_l) * NTRI + t0 + q * 4;
      float4 wv = *(const float4*)wrow;
      wS[q * 4 + 0][o_l] = wv.x;
      wS[q * 4 + 1][o_l] = wv.y;
      wS[q * 4 + 2][o_l] = wv.z;
      wS[q * 4 + 3][o_l] = wv.w;
    }
    // Compute up chunk: upS[t_l][pl] = outS[i][pl]*outS[j][pl]
    {
      int pl = tid & 63;
      int tq = tid >> 6;   // 0..3, wave-uniform
#pragma unroll
      for (int s = 0; s < 4; ++s) {
        int t_l = tq * 4 + s;
        int t = t0 + t_l;
        int i = triI[t];
        int j = triJ[t];
        upS[t_l][pl] = outS[i][pl] * outS[j][pl];
      }
    }
    __syncthreads();
#pragma unroll
    for (int k = 0; k < 16; ++k) {
      float4 wv = *(const float4*)&wS[k][oy * 4];
      float4 uv = *(const float4*)&upS[k][px * 4];
      const float wa[4] = {wv.x, wv.y, wv.z, wv.w};
      const float ua[4] = {uv.x, uv.y, uv.z, uv.w};
#pragma unroll
      for (int a = 0; a < 4; ++a)
#pragma unroll
        for (int bb = 0; bb < 4; ++bb) acc[a][bb] += wa[a] * ua[bb];
    }
    __syncthreads();
  }

  // Epilogue: signed sqrt + coalesced float4 stores
  float* yb = y + ((size_t)b * COUT + o0 + oy * 4) * HW + p0 + px * 4;
#pragma unroll
  for (int a = 0; a < 4; ++a) {
    float4 r;
    float* rp = &r.x;
#pragma unroll
    for (int bb = 0; bb < 4; ++bb) {
      float v = acc[a][bb];
      float s = sqrtf(fabsf(v) + 1e-6f);
      rp[bb] = v > 0.0f ? s : (v < 0.0f ? -s : 0.0f);
    }
    *(float4*)(yb + (size_t)a * HW) = r;
  }
}

extern "C" void kernel_launch(void* const* d_in, const int* in_sizes, int n_in,
                              void* d_out, int out_size, void* d_ws, size_t ws_size,
                              hipStream_t stream) {
  const float* x         = (const float*)d_in[0];
  const float* w_reduce  = (const float*)d_in[1];
  const float* w_recover = (const float*)d_in[2];
  float* y   = (float*)d_out;
  float* out = (float*)d_ws;   // [8][32][9216] = 9.4 MB scratch

  reduce_kernel<<<(NB * HW) / 256, 256, 0, stream>>>(x, w_reduce, out);
  recover_kernel<<<(NB * (HW / 64)) * (COUT / 64), 256, 0, stream>>>(out, w_recover, y);
}

// Round 2
// 268.165 us; speedup vs baseline: 1.8755x; 1.8755x over previous
//
#include <hip/hip_runtime.h>
#include <hip/hip_bf16.h>
#include <math.h>

// Problem constants (BilinearGate): B=8, Cin=256, H=W=96 -> HW=9216, R=32,
// TRI = R*(R+1)/2 = 528, Cout=256.
#define HW    9216
#define CIN   256
#define RCH   32
#define NTRI  528
#define COUT  256
#define NB    8

typedef _Float16 f16x8 __attribute__((ext_vector_type(8)));
typedef float    f32x4 __attribute__((ext_vector_type(4)));

// ---------------------------------------------------------------------------
// Kernel 1: reduce  out[b][r][p] = sum_c x[b][c][p] * w_reduce[r][c]
// K-split by 4: block = 64 px, 4 waves; wave wv handles c in [64*wv, 64*wv+64)
// for all 32 r. Grid 1152 blocks = 4608 waves (~4.5/SIMD) vs round-1's 1.1.
// readfirstlane(tid>>6) keeps the w_reduce index provably wave-uniform so the
// compiler emits s_load + v_fma(sgpr) instead of per-lane vector loads.
// LDS partial[4][32][64] + tree-sum epilogue.
// ---------------------------------------------------------------------------
__global__ __launch_bounds__(256) void reduce_kernel(
    const float* __restrict__ x, const float* __restrict__ w_reduce,
    float* __restrict__ out) {
  __shared__ float partialS[4 * RCH * 64];   // 32 KB
  const int tid = threadIdx.x;
  const int bx = blockIdx.x;                 // 1152
  const int b = bx / 144;
  const int p0 = (bx - b * 144) * 64;
  const int wv = __builtin_amdgcn_readfirstlane(tid >> 6);  // 0..3, SGPR
  const int lane = tid & 63;

  const float* xb = x + ((size_t)(b * CIN + wv * 64)) * HW + p0 + lane;
  const float* wb = w_reduce + wv * 64;

  float acc[RCH];
#pragma unroll
  for (int r = 0; r < RCH; ++r) acc[r] = 0.0f;

#pragma unroll 4
  for (int cc = 0; cc < 64; ++cc) {
    float xv = xb[(size_t)cc * HW];
#pragma unroll
    for (int r = 0; r < RCH; ++r) acc[r] += xv * wb[r * CIN + cc];
  }

#pragma unroll
  for (int r = 0; r < RCH; ++r) partialS[(wv * RCH + r) * 64 + lane] = acc[r];
  __syncthreads();

#pragma unroll
  for (int k = 0; k < 8; ++k) {
    int flat = tid + k * 256;            // 0..2047 = 32 r x 64 p
    int r = flat >> 6;
    int p = flat & 63;
    float s = partialS[r * 64 + p] + partialS[(RCH + r) * 64 + p] +
              partialS[(2 * RCH + r) * 64 + p] + partialS[(3 * RCH + r) * 64 + p];
    out[((size_t)(b * RCH + r)) * HW + p0 + p] = s;
  }
}

// ---------------------------------------------------------------------------
// Kernel 2: recover via MFMA fp16. Block = 64 o x 64 px, K=528 padded to 544
// (17 chunks of 32). Per chunk: stage w chunk (fp32->fp16) into wS[o][32+8],
// compute up chunk (fp32 mul of staged outS, ->fp16) into upS[p][32+8].
// 4 waves in 2x2 (wo,wp); each wave: 2 A-frags + 2 B-frags (ds_read_b128) and
// 4x mfma_f32_16x16x32_f16 per chunk. Fragment layouts (verified m89/m120):
//   A[m=lane&15][k=(lane>>4)*8+j], B[k=(lane>>4)*8+j][n=lane&15],
//   D[row=(lane>>4)*4+reg][col=lane&15].
// Epilogue: signed sqrt, dword stores (16 consecutive px per quarter-wave).
// ---------------------------------------------------------------------------
#define ROWH 40   // padded LDS row length in halfs (80 B) for wS/upS

__global__ __launch_bounds__(256) void recover_kernel(
    const float* __restrict__ out, const float* __restrict__ w_recover,
    float* __restrict__ y) {
  __shared__ float outS[RCH * 64];                       // 8 KB, fp32
  __shared__ __align__(16) _Float16 wS[64 * ROWH];       // 5 KB
  __shared__ __align__(16) _Float16 upS[64 * ROWH];      // 5 KB
  __shared__ short triI[NTRI];
  __shared__ short triJ[NTRI];

  const int tid = threadIdx.x;
  const int bx = blockIdx.x;            // 4608 blocks
  const int ot = bx & 3;                // 4 o-tiles
  const int pt = bx >> 2;               // 1152 pixel tiles (144 per batch)
  const int b = pt / 144;
  const int p0 = (pt - b * 144) * 64;
  const int o0 = ot * 64;

  // Build triu index tables (closed-form inverse + integer fixup).
  for (int t = tid; t < NTRI; t += 256) {
    float disc = 4225.0f - 8.0f * (float)t;
    int i = (int)floorf((65.0f - sqrtf(disc)) * 0.5f);
    while ((i + 1) * (65 - (i + 1)) / 2 <= t) ++i;
    while (i * (65 - i) / 2 > t) --i;
    triI[t] = (short)i;
    triJ[t] = (short)(i + t - i * (65 - i) / 2);
  }

  // Stage out tile (fp32): outS[r*64 + pl]
  {
    const float* ob = out + (size_t)b * RCH * HW + p0;
#pragma unroll
    for (int k = 0; k < 8; ++k) {
      int idx = tid + k * 256;
      int r = idx >> 6;
      int pl = idx & 63;
      outS[idx] = ob[(size_t)r * HW + pl];
    }
  }
  __syncthreads();

  const int wv = tid >> 6;     // wave 0..3
  const int lane = tid & 63;
  const int wo = wv & 1;       // o half (32 rows)
  const int wp = wv >> 1;      // px half (32 cols)
  const int ml = lane & 15;
  const int q = lane >> 4;

  f32x4 acc00 = {0.f, 0.f, 0.f, 0.f};
  f32x4 acc01 = {0.f, 0.f, 0.f, 0.f};
  f32x4 acc10 = {0.f, 0.f, 0.f, 0.f};
  f32x4 acc11 = {0.f, 0.f, 0.f, 0.f};

  // staging roles
  const int w_ol = tid >> 2;          // 0..63 : o row for w staging
  const int w_qq = tid & 3;           // 0..3  : 8-elem group
  const int u_p  = tid & 63;          // pixel for up staging
  const int u_g  = tid >> 6;          // 0..3  : 8-elem t group

  for (int chunk = 0; chunk < 17; ++chunk) {
    const int t0 = chunk * 32;
    // ---- stage w chunk: wS[o][t_l] = fp16(w_recover[o0+o][t0+t_l]), 0 pad
    {
      const int tb = t0 + w_qq * 8;
      f16x8 wv8;
      if (tb < NTRI) {   // 528 % 8 == 0 -> whole group in-bounds
        const float* wr = w_recover + (size_t)(o0 + w_ol) * NTRI + tb;
        float4 w0 = *(const float4*)wr;
        float4 w1 = *(const float4*)(wr + 4);
        wv8[0] = (_Float16)w0.x; wv8[1] = (_Float16)w0.y;
        wv8[2] = (_Float16)w0.z; wv8[3] = (_Float16)w0.w;
        wv8[4] = (_Float16)w1.x; wv8[5] = (_Float16)w1.y;
        wv8[6] = (_Float16)w1.z; wv8[7] = (_Float16)w1.w;
      } else {
#pragma unroll
        for (int s = 0; s < 8; ++s) wv8[s] = (_Float16)0.0f;
      }
      *(f16x8*)&wS[w_ol * ROWH + w_qq * 8] = wv8;
    }
    // ---- stage up chunk: upS[p][t_l] = fp16(out[i]*out[j]), 0 pad
    {
      f16x8 uv8;
#pragma unroll
      for (int s = 0; s < 8; ++s) {
        int t = t0 + u_g * 8 + s;
        float v = 0.0f;
        if (t < NTRI) {
          int i = triI[t];
          int j = triJ[t];
          v = outS[i * 64 + u_p] * outS[j * 64 + u_p];
        }
        uv8[s] = (_Float16)v;
      }
      *(f16x8*)&upS[u_p * ROWH + u_g * 8] = uv8;
    }
    __syncthreads();
    // ---- MFMA phase
    {
      f16x8 a0 = *(const f16x8*)&wS[(wo * 32 + ml) * ROWH + q * 8];
      f16x8 a1 = *(const f16x8*)&wS[(wo * 32 + 16 + ml) * ROWH + q * 8];
      f16x8 b0 = *(const f16x8*)&upS[(wp * 32 + ml) * ROWH + q * 8];
      f16x8 b1 = *(const f16x8*)&upS[(wp * 32 + 16 + ml) * ROWH + q * 8];
      acc00 = __builtin_amdgcn_mfma_f32_16x16x32_f16(a0, b0, acc00, 0, 0, 0);
      acc01 = __builtin_amdgcn_mfma_f32_16x16x32_f16(a0, b1, acc01, 0, 0, 0);
      acc10 = __builtin_amdgcn_mfma_f32_16x16x32_f16(a1, b0, acc10, 0, 0, 0);
      acc11 = __builtin_amdgcn_mfma_f32_16x16x32_f16(a1, b1, acc11, 0, 0, 0);
    }
    __syncthreads();
  }

  // Epilogue: D[row=q*4+reg][col=ml]; signed sqrt; dword stores.
  const float* accs[2][2] = {{(const float*)&acc00, (const float*)&acc01},
                             {(const float*)&acc10, (const float*)&acc11}};
#pragma unroll
  for (int mi = 0; mi < 2; ++mi) {
#pragma unroll
    for (int reg = 0; reg < 4; ++reg) {
      int o = o0 + wo * 32 + mi * 16 + q * 4 + reg;
      float* yrow = y + ((size_t)(b * COUT + o)) * HW + p0 + wp * 32 + ml;
#pragma unroll
      for (int ni = 0; ni < 2; ++ni) {
        float v = accs[mi][ni][reg];
        float s = sqrtf(fabsf(v) + 1e-6f);
        yrow[ni * 16] = v > 0.0f ? s : (v < 0.0f ? -s : 0.0f);
      }
    }
  }
}

extern "C" void kernel_launch(void* const* d_in, const int* in_sizes, int n_in,
                              void* d_out, int out_size, void* d_ws, size_t ws_size,
                              hipStream_t stream) {
  const float* x         = (const float*)d_in[0];
  const float* w_reduce  = (const float*)d_in[1];
  const float* w_recover = (const float*)d_in[2];
  float* y   = (float*)d_out;
  float* out = (float*)d_ws;   // [8][32][9216] fp32 = 9.4 MB scratch

  reduce_kernel<<<NB * (HW / 64), 256, 0, stream>>>(x, w_reduce, out);
  recover_kernel<<<(NB * (HW / 64)) * (COUT / 64), 256, 0, stream>>>(out, w_recover, y);
}

// Round 3
// 232.581 us; speedup vs baseline: 2.1624x; 1.1530x over previous
//
#include <hip/hip_runtime.h>
#include <hip/hip_bf16.h>
#include <math.h>

// BilinearGate fused single kernel. B=8, Cin=256, HW=9216, R=32, TRI=528,
// Cout=256. Block = 64 px (one per block, 1152 blocks), 256 threads (4 waves).
// Phase 1: out[32][64] = w_reduce @ x  via split-fp16 MFMA (3-term: hi*hi +
//          hi*lo + lo*hi => fp32-accurate, keeps absmax at the fp16-up level).
// Phase 2: y = signed_sqrt(w_recover @ up(out)) via fp16 MFMA, all 256 o per
//          block so the up-staging VALU cost is paid once per px-tile (r2 paid
//          it 4x) and the out round-trip through HBM is eliminated.
#define HW    9216
#define CIN   256
#define RCH   32
#define NTRI  528
#define COUT  256
#define NB    8

typedef _Float16 f16x8 __attribute__((ext_vector_type(8)));
typedef _Float16 f16x4 __attribute__((ext_vector_type(4)));
typedef float    f32x4 __attribute__((ext_vector_type(4)));

#define XROW 72   // halfs per xh/xl row (64 + 8 pad) = 144 B, 16B-multiple
#define WROW 40   // halfs per wrec/up row (32 + 8 pad) = 80 B, 16B-multiple

__global__ __launch_bounds__(256, 4) void fused_kernel(
    const float* __restrict__ x, const float* __restrict__ w_reduce,
    const float* __restrict__ w_recover, float* __restrict__ y) {
  __shared__ float outS[RCH * 68];          // 8.5 KB, fp32 reduce output
  __shared__ short triI[NTRI];
  __shared__ short triJ[NTRI];
  __shared__ __align__(16) union {
    struct { _Float16 xh[64 * XROW]; _Float16 xl[64 * XROW]; } g1;   // 18 KB
    struct { _Float16 wrec[COUT * WROW]; _Float16 up[64 * WROW]; } g2; // 25 KB
  } su;

  const int tid = threadIdx.x;
  const int bx = blockIdx.x;           // 1152 = 8 b * 144 px-tiles
  const int b  = bx / 144;
  const int p0 = (bx - b * 144) * 64;

  const int wv   = tid >> 6;           // wave 0..3
  const int lane = tid & 63;
  const int ml   = lane & 15;
  const int q    = lane >> 4;

  // triu index tables (closed-form inverse + fixup)
  for (int t = tid; t < NTRI; t += 256) {
    float disc = 4225.0f - 8.0f * (float)t;
    int i = (int)floorf((65.0f - sqrtf(disc)) * 0.5f);
    while ((i + 1) * (65 - (i + 1)) / 2 <= t) ++i;
    while (i * (65 - i) / 2 > t) --i;
    triI[t] = (short)i;
    triJ[t] = (short)(i + t - i * (65 - i) / 2);
  }

  // ------------------- Phase 1: GEMM1, split-fp16 MFMA ---------------------
  // out[r][p] = sum_c w_reduce[r][c] * x[b][c][p0+p].  K=256 in 4 chunks of
  // 64.  A = w (rows r, frag A[m=ml][k=q*8+j], per-lane global loads -- w is
  // 32 KB, L1/L2 resident).  B = x staged TRANSPOSED in LDS: xS[px][c_local],
  // hi+lo fp16.  Wave wv owns px tile wv*16; both m-tiles (32 r).
  {
    f32x4 g1acc[2];
#pragma unroll
    for (int mt = 0; mt < 2; ++mt)
#pragma unroll
      for (int r2 = 0; r2 < 4; ++r2) g1acc[mt][r2] = 0.0f;

    const int c4 = (tid & 15) * 4;     // c_local group
    const int p4 = (tid >> 4) * 4;     // px group
    for (int ch = 0; ch < 4; ++ch) {
      const int c0 = ch * 64;
      // stage: 4c x 4px register-block transpose, f16x4 LDS stores
      float vbl[4][4];
#pragma unroll
      for (int i2 = 0; i2 < 4; ++i2) {
        float4 xv = *(const float4*)&x[((size_t)(b * CIN + c0 + c4 + i2)) * HW + p0 + p4];
        vbl[i2][0] = xv.x; vbl[i2][1] = xv.y; vbl[i2][2] = xv.z; vbl[i2][3] = xv.w;
      }
#pragma unroll
      for (int j2 = 0; j2 < 4; ++j2) {
        f16x4 hi, lo;
#pragma unroll
        for (int i2 = 0; i2 < 4; ++i2) {
          float f = vbl[i2][j2];
          _Float16 h = (_Float16)f;
          hi[i2] = h;
          lo[i2] = (_Float16)(f - (float)h);
        }
        *(f16x4*)&su.g1.xh[(p4 + j2) * XROW + c4] = hi;
        *(f16x4*)&su.g1.xl[(p4 + j2) * XROW + c4] = lo;
      }
      __syncthreads();
#pragma unroll
      for (int ks = 0; ks < 2; ++ks) {
        f16x8 bh = *(const f16x8*)&su.g1.xh[(wv * 16 + ml) * XROW + ks * 32 + q * 8];
        f16x8 bl = *(const f16x8*)&su.g1.xl[(wv * 16 + ml) * XROW + ks * 32 + q * 8];
#pragma unroll
        for (int mt = 0; mt < 2; ++mt) {
          const float* wr = w_reduce + (mt * 16 + ml) * CIN + c0 + ks * 32 + q * 8;
          float4 w0 = *(const float4*)wr;
          float4 w1 = *(const float4*)(wr + 4);
          float wf[8] = {w0.x, w0.y, w0.z, w0.w, w1.x, w1.y, w1.z, w1.w};
          f16x8 ah, al;
#pragma unroll
          for (int s = 0; s < 8; ++s) {
            _Float16 h = (_Float16)wf[s];
            ah[s] = h;
            al[s] = (_Float16)(wf[s] - (float)h);
          }
          g1acc[mt] = __builtin_amdgcn_mfma_f32_16x16x32_f16(ah, bh, g1acc[mt], 0, 0, 0);
          g1acc[mt] = __builtin_amdgcn_mfma_f32_16x16x32_f16(ah, bl, g1acc[mt], 0, 0, 0);
          g1acc[mt] = __builtin_amdgcn_mfma_f32_16x16x32_f16(al, bh, g1acc[mt], 0, 0, 0);
        }
      }
      __syncthreads();
    }
    // D[row=q*4+reg][col=ml]: r = mt*16+q*4+reg, p = wv*16+ml
#pragma unroll
    for (int mt = 0; mt < 2; ++mt)
#pragma unroll
      for (int reg = 0; reg < 4; ++reg)
        outS[(mt * 16 + q * 4 + reg) * 68 + wv * 16 + ml] = g1acc[mt][reg];
  }
  __syncthreads();

  // ------------------- Phase 2: GEMM2, fp16 MFMA ---------------------------
  // Wave wv owns o in [wv*64, wv*64+64) (4 m-tiles) x all 64 px (4 n-tiles).
  f32x4 acc[4][4];
#pragma unroll
  for (int mi = 0; mi < 4; ++mi)
#pragma unroll
    for (int ni = 0; ni < 4; ++ni)
#pragma unroll
      for (int r2 = 0; r2 < 4; ++r2) acc[mi][ni][r2] = 0.0f;

  const int wr_row = tid >> 3;        // 0..31
  const int k4 = (tid & 7) * 4;       // 0..28
  const int u_p = tid & 63;
  const int u_g = tid >> 6;

  for (int chunk = 0; chunk < 17; ++chunk) {
    const int t0 = chunk * 32;
    // stage w_recover chunk: 256 o x 32 k, fp32->fp16, 8 passes x 32 rows,
    // lanes 0..7 cover 128B contiguous per row. Zero-pad beyond t=528.
#pragma unroll
    for (int pass = 0; pass < 8; ++pass) {
      const int o = pass * 32 + wr_row;
      f16x4 hv;
      if (t0 + k4 < NTRI) {
        float4 w4 = *(const float4*)&w_recover[(size_t)o * NTRI + t0 + k4];
        hv[0] = (_Float16)w4.x; hv[1] = (_Float16)w4.y;
        hv[2] = (_Float16)w4.z; hv[3] = (_Float16)w4.w;
      } else {
        hv[0] = hv[1] = hv[2] = hv[3] = (_Float16)0.0f;
      }
      *(f16x4*)&su.g2.wrec[o * WROW + k4] = hv;
    }
    // stage up chunk: up[p][t_l] = fp16(out[i][p]*out[j][p]) -- once per
    // px-tile (the fusion win; r2 recomputed this per o-tile block)
    {
      f16x8 uv8;
#pragma unroll
      for (int s = 0; s < 8; ++s) {
        int t = t0 + u_g * 8 + s;
        float v = 0.0f;
        if (t < NTRI) {
          int i = triI[t];
          int j = triJ[t];
          v = outS[i * 68 + u_p] * outS[j * 68 + u_p];
        }
        uv8[s] = (_Float16)v;
      }
      *(f16x8*)&su.g2.up[u_p * WROW + u_g * 8] = uv8;
    }
    __syncthreads();
    // 16 MFMA per wave per chunk
    f16x8 bfr[4];
#pragma unroll
    for (int ni = 0; ni < 4; ++ni)
      bfr[ni] = *(const f16x8*)&su.g2.up[(ni * 16 + ml) * WROW + q * 8];
#pragma unroll
    for (int mi = 0; mi < 4; ++mi) {
      f16x8 afr = *(const f16x8*)&su.g2.wrec[(wv * 64 + mi * 16 + ml) * WROW + q * 8];
#pragma unroll
      for (int ni = 0; ni < 4; ++ni)
        acc[mi][ni] = __builtin_amdgcn_mfma_f32_16x16x32_f16(afr, bfr[ni], acc[mi][ni], 0, 0, 0);
    }
    __syncthreads();
  }

  // Epilogue: D[row=q*4+reg][col=ml]; signed sqrt; dword stores (4x64B
  // segments per instruction).
#pragma unroll
  for (int mi = 0; mi < 4; ++mi) {
#pragma unroll
    for (int reg = 0; reg < 4; ++reg) {
      const int o = wv * 64 + mi * 16 + q * 4 + reg;
      float* yrow = y + ((size_t)(b * COUT + o)) * HW + p0 + ml;
#pragma unroll
      for (int ni = 0; ni < 4; ++ni) {
        float v = acc[mi][ni][reg];
        float s = sqrtf(fabsf(v) + 1e-6f);
        yrow[ni * 16] = v > 0.0f ? s : (v < 0.0f ? -s : 0.0f);
      }
    }
  }
}

extern "C" void kernel_launch(void* const* d_in, const int* in_sizes, int n_in,
                              void* d_out, int out_size, void* d_ws, size_t ws_size,
                              hipStream_t stream) {
  const float* x         = (const float*)d_in[0];
  const float* w_reduce  = (const float*)d_in[1];
  const float* w_recover = (const float*)d_in[2];
  float* y = (float*)d_out;

  fused_kernel<<<NB * (HW / 64), 256, 0, stream>>>(x, w_reduce, w_recover, y);
}

// Round 4
// 192.578 us; speedup vs baseline: 2.6116x; 1.2077x over previous
//
#include <hip/hip_runtime.h>
#include <hip/hip_bf16.h>
#include <math.h>

// BilinearGate fused. B=8, Cin=256, HW=9216, R=32, TRI=528, Cout=256.
// convert_kernel: w_recover -> fp16 [256][544] (zero-padded), w_reduce ->
//   hi/lo fp16 split (3-term trick keeps GEMM1 fp32-accurate).
// fused_kernel: block = 64 px, 4 waves.
//   Phase 1: out[32][64] = w_reduce @ x, split-fp16 MFMA, x staged transposed
//            in double-buffered LDS (1 barrier/chunk), A-frags from global.
//   Phase 2: y = signed_sqrt(w_recover @ up(out)), fp16 MFMA; up (only) in
//            double-buffered LDS, w A-frags DIRECT FROM GLOBAL (L2-resident,
//            no barrier dependency -> prefetchable), 1 barrier/chunk.
#define HW     9216
#define CIN    256
#define RCH    32
#define NTRI   528
#define COUT   256
#define NB     8
#define W16ROW 544   // padded fp16 w_recover row: 17 chunks * 32
#define UROW   40    // 32 k + 8 pad halfs (80 B rows: 2-way LDS aliasing only)
#define XROW2  40    // 32 c + 8 pad halfs

typedef _Float16 f16x8 __attribute__((ext_vector_type(8)));
typedef _Float16 f16x4 __attribute__((ext_vector_type(4)));
typedef float    f32x4 __attribute__((ext_vector_type(4)));

__global__ __launch_bounds__(256) void convert_kernel(
    const float* __restrict__ w_reduce, const float* __restrict__ w_recover,
    _Float16* __restrict__ w16, _Float16* __restrict__ wr16h,
    _Float16* __restrict__ wr16l) {
  const int bx = blockIdx.x;
  const int tid = threadIdx.x;
  if (bx < COUT) {
    for (int t = tid; t < W16ROW; t += 256) {
      float f = (t < NTRI) ? w_recover[(size_t)bx * NTRI + t] : 0.0f;
      w16[(size_t)bx * W16ROW + t] = (_Float16)f;
    }
  } else {
    int e = (bx - COUT) * 512 + tid;
#pragma unroll
    for (int k = 0; k < 2; ++k, e += 256) {
      float f = w_reduce[e];
      _Float16 h = (_Float16)f;
      wr16h[e] = h;
      wr16l[e] = (_Float16)(f - (float)h);
    }
  }
}

__global__ __launch_bounds__(256, 4) void fused_kernel(
    const float* __restrict__ x, const _Float16* __restrict__ w16,
    const _Float16* __restrict__ wr16h, const _Float16* __restrict__ wr16l,
    float* __restrict__ y) {
  __shared__ float outS[RCH * 68];          // 8.5 KB fp32 GEMM1 result
  __shared__ short triI[NTRI];
  __shared__ short triJ[NTRI];
  __shared__ __align__(16) union {
    struct { _Float16 xh[2][64 * XROW2]; _Float16 xl[2][64 * XROW2]; } g1; // 20.5 KB
    struct { _Float16 up[2][64 * UROW]; } g2;                              // 10 KB
  } su;

  const int tid = threadIdx.x;
  const int bx = blockIdx.x;           // 1152 = 8 b * 144 px-tiles
  const int b  = bx / 144;
  const int p0 = (bx - b * 144) * 64;

  const int wv   = tid >> 6;           // wave 0..3
  const int lane = tid & 63;
  const int ml   = lane & 15;
  const int q    = lane >> 4;

  // triu index tables (used in phase 2; phase-1 barriers cover the hazard)
  for (int t = tid; t < NTRI; t += 256) {
    float disc = 4225.0f - 8.0f * (float)t;
    int i = (int)floorf((65.0f - sqrtf(disc)) * 0.5f);
    while ((i + 1) * (65 - (i + 1)) / 2 <= t) ++i;
    while (i * (65 - i) / 2 > t) --i;
    triI[t] = (short)i;
    triJ[t] = (short)(i + t - i * (65 - i) / 2);
  }

  // ------------------- Phase 1: GEMM1, split-fp16 MFMA ---------------------
  // out[r][p] = sum_c w_reduce[r][c]*x[b][c][p0+p]; K=256 in 8 chunks of 32.
  // A (w hi/lo) direct from global (L1-resident 32 KB); B (x^T) hi/lo staged
  // in double-buffered LDS, one barrier per chunk.
  {
    f32x4 g1acc[2];
#pragma unroll
    for (int mt = 0; mt < 2; ++mt)
#pragma unroll
      for (int r2 = 0; r2 < 4; ++r2) g1acc[mt][r2] = 0.0f;

    const int c4 = (tid & 7) * 4;      // 4 c rows
    const int p2 = (tid >> 3) * 2;     // 2 px
    for (int ch = 0; ch < 8; ++ch) {
      const int cur = ch & 1;
      const int c0 = ch * 32;
      // A-fragment prefetch (global, no LDS dependency)
      f16x8 ah[2], al[2];
#pragma unroll
      for (int mt = 0; mt < 2; ++mt) {
        const int off = (mt * 16 + ml) * CIN + c0 + q * 8;
        ah[mt] = *(const f16x8*)&wr16h[off];
        al[mt] = *(const f16x8*)&wr16l[off];
      }
      // stage x chunk: 4c x 2px per thread, transpose, hi/lo split
      float v[4][2];
#pragma unroll
      for (int i2 = 0; i2 < 4; ++i2) {
        float2 xv = *(const float2*)&x[((size_t)(b * CIN + c0 + c4 + i2)) * HW + p0 + p2];
        v[i2][0] = xv.x; v[i2][1] = xv.y;
      }
#pragma unroll
      for (int jp = 0; jp < 2; ++jp) {
        f16x4 hi, lo;
#pragma unroll
        for (int i2 = 0; i2 < 4; ++i2) {
          float f = v[i2][jp];
          _Float16 h = (_Float16)f;
          hi[i2] = h;
          lo[i2] = (_Float16)(f - (float)h);
        }
        *(f16x4*)&su.g1.xh[cur][(p2 + jp) * XROW2 + c4] = hi;
        *(f16x4*)&su.g1.xl[cur][(p2 + jp) * XROW2 + c4] = lo;
      }
      __syncthreads();
      f16x8 bh = *(const f16x8*)&su.g1.xh[cur][(wv * 16 + ml) * XROW2 + q * 8];
      f16x8 bl = *(const f16x8*)&su.g1.xl[cur][(wv * 16 + ml) * XROW2 + q * 8];
#pragma unroll
      for (int mt = 0; mt < 2; ++mt) {
        g1acc[mt] = __builtin_amdgcn_mfma_f32_16x16x32_f16(ah[mt], bh, g1acc[mt], 0, 0, 0);
        g1acc[mt] = __builtin_amdgcn_mfma_f32_16x16x32_f16(al[mt], bh, g1acc[mt], 0, 0, 0);
        g1acc[mt] = __builtin_amdgcn_mfma_f32_16x16x32_f16(ah[mt], bl, g1acc[mt], 0, 0, 0);
      }
      // no second barrier: next chunk writes the other buffer; barriers are
      // collective so no wave can lap another by a full buffer.
    }
    // D[row=q*4+reg][col=ml]: r = mt*16+q*4+reg, p = wv*16+ml
#pragma unroll
    for (int mt = 0; mt < 2; ++mt)
#pragma unroll
      for (int reg = 0; reg < 4; ++reg)
        outS[(mt * 16 + q * 4 + reg) * 68 + wv * 16 + ml] = g1acc[mt][reg];
  }
  __syncthreads();   // outS ready; g1 LDS reads done -> g2 may overwrite union

  // ------------------- Phase 2: GEMM2, fp16 MFMA ---------------------------
  // Wave wv: o in [wv*64, wv*64+64) x all 64 px. A-frags direct from global
  // w16 (L2-resident, zero-padded rows); up double-buffered, 1 barrier/chunk.
  f32x4 acc[4][4];
#pragma unroll
  for (int mi = 0; mi < 4; ++mi)
#pragma unroll
    for (int ni = 0; ni < 4; ++ni)
#pragma unroll
      for (int r2 = 0; r2 < 4; ++r2) acc[mi][ni][r2] = 0.0f;

  const int u_p = lane;   // pixel for up staging
  const int u_g = wv;     // 8-elem t group

  for (int chunk = 0; chunk < 17; ++chunk) {
    const int cur = chunk & 1;
    const int t0 = chunk * 32;
    // A-fragment prefetch (global; rows pre-padded with zeros past t=528)
    f16x8 afr[4];
#pragma unroll
    for (int mi = 0; mi < 4; ++mi)
      afr[mi] = *(const f16x8*)&w16[(size_t)(wv * 64 + mi * 16 + ml) * W16ROW + t0 + q * 8];
    // stage up chunk: up[p][t_l] = fp16(out[i][p]*out[j][p])
    {
      f16x8 uv8;
#pragma unroll
      for (int s = 0; s < 8; ++s) {
        int t = t0 + u_g * 8 + s;
        float v = 0.0f;
        if (t < NTRI) {
          int i = triI[t];
          int j = triJ[t];
          v = outS[i * 68 + u_p] * outS[j * 68 + u_p];
        }
        uv8[s] = (_Float16)v;
      }
      *(f16x8*)&su.g2.up[cur][u_p * UROW + u_g * 8] = uv8;
    }
    __syncthreads();
    f16x8 bfr[4];
#pragma unroll
    for (int ni = 0; ni < 4; ++ni)
      bfr[ni] = *(const f16x8*)&su.g2.up[cur][(ni * 16 + ml) * UROW + q * 8];
#pragma unroll
    for (int mi = 0; mi < 4; ++mi)
#pragma unroll
      for (int ni = 0; ni < 4; ++ni)
        acc[mi][ni] = __builtin_amdgcn_mfma_f32_16x16x32_f16(afr[mi], bfr[ni], acc[mi][ni], 0, 0, 0);
    // single barrier per chunk (double buffer)
  }

  // Epilogue: D[row=q*4+reg][col=ml]; signed sqrt; dword stores.
#pragma unroll
  for (int mi = 0; mi < 4; ++mi) {
#pragma unroll
    for (int reg = 0; reg < 4; ++reg) {
      const int o = wv * 64 + mi * 16 + q * 4 + reg;
      float* yrow = y + ((size_t)(b * COUT + o)) * HW + p0 + ml;
#pragma unroll
      for (int ni = 0; ni < 4; ++ni) {
        float v = acc[mi][ni][reg];
        float s = sqrtf(fabsf(v) + 1e-6f);
        yrow[ni * 16] = v > 0.0f ? s : (v < 0.0f ? -s : 0.0f);
      }
    }
  }
}

extern "C" void kernel_launch(void* const* d_in, const int* in_sizes, int n_in,
                              void* d_out, int out_size, void* d_ws, size_t ws_size,
                              hipStream_t stream) {
  const float* x         = (const float*)d_in[0];
  const float* w_reduce  = (const float*)d_in[1];
  const float* w_recover = (const float*)d_in[2];
  float* y = (float*)d_out;

  _Float16* w16   = (_Float16*)d_ws;                            // 256*544*2 = 278528 B
  _Float16* wr16h = (_Float16*)((char*)d_ws + 278528);          // 32*256*2  = 16384 B
  _Float16* wr16l = (_Float16*)((char*)d_ws + 278528 + 16384);  // 16384 B

  convert_kernel<<<COUT + 16, 256, 0, stream>>>(w_reduce, w_recover, w16, wr16h, wr16l);
  fused_kernel<<<NB * (HW / 64), 256, 0, stream>>>(x, w16, wr16h, wr16l, y);
}

// Round 5
// 179.372 us; speedup vs baseline: 2.8039x; 1.0736x over previous
//
#include <hip/hip_runtime.h>
#include <hip/hip_bf16.h>
#include <math.h>

// BilinearGate fused, free-run structure. B=8, Cin=256, HW=9216, R=32,
// TRI=528, Cout=256. Block = 64 px, 4 waves, 1152 blocks.
// Phase 1 (no LDS, no barriers): out[32][64] = w_reduce @ x, split-fp16 MFMA
//   (3-term hi/lo => fp32-accurate). B-frags from strided global x loads.
// up-build: up[px][t] materialized in LDS ONCE per half (288 + 256 t), with
//   COMPILE-TIME triu indices (constexpr table + per-wave template) -> pure
//   v_mul/cvt on statically-indexed regs; no tri reads, no dynamic indexing.
// Phase 2 (free-run): per half, chunks of K=32 with A direct from global
//   (L2-resident fp16 w16, zero-padded rows), B from LDS b128, 16 MFMA/chunk;
//   NO barriers inside the chunk loops. 5 barriers in the whole kernel.
#define HW     9216
#define CIN    256
#define RCH    32
#define NTRI   528
#define COUT   256
#define NB     8
#define W16ROW 544   // fp16 w_recover row: 17*32, zero-padded past 528
#define UPROW  296   // halfs per upS row (288 data + 8 pad) = 592 B = 37*16

typedef _Float16 f16x8 __attribute__((ext_vector_type(8)));
typedef float    f32x4 __attribute__((ext_vector_type(4)));

struct TriTab { unsigned char i[544]; unsigned char j[544]; };
constexpr TriTab make_tri() {
  TriTab t{};
  int ii = 0, jj = 0;
  for (int k = 0; k < 544; ++k) {
    if (k < NTRI) {
      t.i[k] = (unsigned char)ii; t.j[k] = (unsigned char)jj;
      if (++jj == 32) { ++ii; jj = ii; }
    } else { t.i[k] = 0; t.j[k] = 0; }
  }
  return t;
}
constexpr TriTab TRI = make_tri();

// Build this wave's share of up[p][t] for one half. TQ = wave id (0..3),
// HALF 0: t in [0,288), 72 t/thread; HALF 1: t in [288,544), 64 t/thread.
// All indices compile-time -> o[] statically indexed, t>=528 folds to 0.
template<int TQ, int HALF>
__device__ __forceinline__ void build_up(const float (&o)[RCH], _Float16* rowp) {
  constexpr int NG  = HALF ? 8 : 9;              // groups of 8 t
  constexpr int TLB = TQ * (HALF ? 64 : 72);     // local base (x2B is 16B-mult)
  constexpr int TB  = HALF ? 288 : 0;            // global t base
#pragma unroll
  for (int g = 0; g < NG; ++g) {
    f16x8 v;
#pragma unroll
    for (int s = 0; s < 8; ++s) {
      const int tl = TLB + g * 8 + s;
      const int t  = TB + tl;
      float f = (t < NTRI) ? o[TRI.i[t]] * o[TRI.j[t]] : 0.0f;
      v[s] = (_Float16)f;
    }
    *(f16x8*)&rowp[TLB + g * 8] = v;
  }
}

template<int HALF>
__device__ __forceinline__ void build_dispatch(int wv, const float (&o)[RCH],
                                               _Float16* rowp) {
  if (wv == 0)      build_up<0, HALF>(o, rowp);
  else if (wv == 1) build_up<1, HALF>(o, rowp);
  else if (wv == 2) build_up<2, HALF>(o, rowp);
  else              build_up<3, HALF>(o, rowp);
}

__global__ __launch_bounds__(256) void convert_kernel(
    const float* __restrict__ w_reduce, const float* __restrict__ w_recover,
    _Float16* __restrict__ w16, _Float16* __restrict__ wr16h,
    _Float16* __restrict__ wr16l) {
  const int bx = blockIdx.x;
  const int tid = threadIdx.x;
  if (bx < COUT) {
    for (int t = tid; t < W16ROW; t += 256) {
      float f = (t < NTRI) ? w_recover[(size_t)bx * NTRI + t] : 0.0f;
      w16[(size_t)bx * W16ROW + t] = (_Float16)f;
    }
  } else {
    int e = (bx - COUT) * 512 + tid;
#pragma unroll
    for (int k = 0; k < 2; ++k, e += 256) {
      float f = w_reduce[e];
      _Float16 h = (_Float16)f;
      wr16h[e] = h;
      wr16l[e] = (_Float16)(f - (float)h);
    }
  }
}

__global__ __launch_bounds__(256, 3) void fused_kernel(
    const float* __restrict__ x, const _Float16* __restrict__ w16,
    const _Float16* __restrict__ wr16h, const _Float16* __restrict__ wr16l,
    float* __restrict__ y) {
  __shared__ float outS[RCH * 68];                     // 8.7 KB
  __shared__ __align__(16) _Float16 upS[64 * UPROW];   // 37.9 KB

  const int tid  = threadIdx.x;
  const int bx   = blockIdx.x;          // 1152 = 8 b * 144 px-tiles
  const int b    = bx / 144;
  const int p0   = (bx - b * 144) * 64;
  const int wv   = tid >> 6;
  const int lane = tid & 63;
  const int ml   = lane & 15;
  const int q    = lane >> 4;

  // ---------------- Phase 1: GEMM1, no LDS, no barriers -------------------
  // Wave wv owns px n-tile wv*16..+16; mt 0..1 cover the 32 r.
  {
    f32x4 g1acc[2];
#pragma unroll
    for (int mt = 0; mt < 2; ++mt)
#pragma unroll
      for (int r2 = 0; r2 < 4; ++r2) g1acc[mt][r2] = 0.0f;

    const float* xb = x + (size_t)b * CIN * HW + p0 + wv * 16 + ml;
#pragma unroll
    for (int ch = 0; ch < 8; ++ch) {
      const int c0 = ch * 32;
      float xv[8];
#pragma unroll
      for (int s = 0; s < 8; ++s)
        xv[s] = xb[(size_t)(c0 + q * 8 + s) * HW];
      f16x8 bh, bl;
#pragma unroll
      for (int s = 0; s < 8; ++s) {
        _Float16 h = (_Float16)xv[s];
        bh[s] = h;
        bl[s] = (_Float16)(xv[s] - (float)h);
      }
#pragma unroll
      for (int mt = 0; mt < 2; ++mt) {
        const int off = (mt * 16 + ml) * CIN + c0 + q * 8;
        f16x8 ah = *(const f16x8*)&wr16h[off];
        f16x8 al = *(const f16x8*)&wr16l[off];
        g1acc[mt] = __builtin_amdgcn_mfma_f32_16x16x32_f16(ah, bh, g1acc[mt], 0, 0, 0);
        g1acc[mt] = __builtin_amdgcn_mfma_f32_16x16x32_f16(al, bh, g1acc[mt], 0, 0, 0);
        g1acc[mt] = __builtin_amdgcn_mfma_f32_16x16x32_f16(ah, bl, g1acc[mt], 0, 0, 0);
      }
    }
    // D[row=q*4+reg][col=ml]: r = mt*16+q*4+reg, p = wv*16+ml
#pragma unroll
    for (int mt = 0; mt < 2; ++mt)
#pragma unroll
      for (int reg = 0; reg < 4; ++reg)
        outS[(mt * 16 + q * 4 + reg) * 68 + wv * 16 + ml] = g1acc[mt][reg];
  }
  __syncthreads();   // barrier 1: outS complete

  f32x4 acc[4][4];
#pragma unroll
  for (int mi = 0; mi < 4; ++mi)
#pragma unroll
    for (int ni = 0; ni < 4; ++ni)
#pragma unroll
      for (int r2 = 0; r2 < 4; ++r2) acc[mi][ni][r2] = 0.0f;

  _Float16* rowp = &upS[lane * UPROW];

  // ---------------- HALF 0: build t[0,288) then free-run chunks 0..8 ------
  {
    float o[RCH];
#pragma unroll
    for (int r = 0; r < RCH; ++r) o[r] = outS[r * 68 + lane];  // 2-way, free
    build_dispatch<0>(wv, o, rowp);
  }
  __syncthreads();   // barrier 2: upS half0 ready
#pragma unroll
  for (int c = 0; c < 9; ++c) {
    const int t0 = c * 32;
    f16x8 afr[4];
#pragma unroll
    for (int mi = 0; mi < 4; ++mi)
      afr[mi] = *(const f16x8*)&w16[(size_t)(wv * 64 + mi * 16 + ml) * W16ROW + t0 + q * 8];
    f16x8 bfr[4];
#pragma unroll
    for (int ni = 0; ni < 4; ++ni)
      bfr[ni] = *(const f16x8*)&upS[(ni * 16 + ml) * UPROW + t0 + q * 8];
#pragma unroll
    for (int mi = 0; mi < 4; ++mi)
#pragma unroll
      for (int ni = 0; ni < 4; ++ni)
        acc[mi][ni] = __builtin_amdgcn_mfma_f32_16x16x32_f16(afr[mi], bfr[ni], acc[mi][ni], 0, 0, 0);
  }
  __syncthreads();   // barrier 3: half0 reads done (WAR before overwrite)

  // ---------------- HALF 1: build t[288,544) then free-run chunks 0..7 ----
  {
    float o[RCH];
#pragma unroll
    for (int r = 0; r < RCH; ++r) o[r] = outS[r * 68 + lane];
    build_dispatch<1>(wv, o, rowp);
  }
  __syncthreads();   // barrier 4: upS half1 ready
#pragma unroll
  for (int c = 0; c < 8; ++c) {
    const int t0l = c * 32;          // local offset in upS
    const int t0g = 288 + c * 32;    // global t for w16
    f16x8 afr[4];
#pragma unroll
    for (int mi = 0; mi < 4; ++mi)
      afr[mi] = *(const f16x8*)&w16[(size_t)(wv * 64 + mi * 16 + ml) * W16ROW + t0g + q * 8];
    f16x8 bfr[4];
#pragma unroll
    for (int ni = 0; ni < 4; ++ni)
      bfr[ni] = *(const f16x8*)&upS[(ni * 16 + ml) * UPROW + t0l + q * 8];
#pragma unroll
    for (int mi = 0; mi < 4; ++mi)
#pragma unroll
      for (int ni = 0; ni < 4; ++ni)
        acc[mi][ni] = __builtin_amdgcn_mfma_f32_16x16x32_f16(afr[mi], bfr[ni], acc[mi][ni], 0, 0, 0);
  }

  // ---------------- Epilogue: signed sqrt, dword stores -------------------
#pragma unroll
  for (int mi = 0; mi < 4; ++mi) {
#pragma unroll
    for (int reg = 0; reg < 4; ++reg) {
      const int o = wv * 64 + mi * 16 + q * 4 + reg;
      float* yrow = y + ((size_t)(b * COUT + o)) * HW + p0 + ml;
#pragma unroll
      for (int ni = 0; ni < 4; ++ni) {
        float v = acc[mi][ni][reg];
        float s = sqrtf(fabsf(v) + 1e-6f);
        yrow[ni * 16] = v > 0.0f ? s : (v < 0.0f ? -s : 0.0f);
      }
    }
  }
}

extern "C" void kernel_launch(void* const* d_in, const int* in_sizes, int n_in,
                              void* d_out, int out_size, void* d_ws, size_t ws_size,
                              hipStream_t stream) {
  const float* x         = (const float*)d_in[0];
  const float* w_reduce  = (const float*)d_in[1];
  const float* w_recover = (const float*)d_in[2];
  float* y = (float*)d_out;

  _Float16* w16   = (_Float16*)d_ws;                            // 256*544*2 = 278528 B
  _Float16* wr16h = (_Float16*)((char*)d_ws + 278528);          // 16384 B
  _Float16* wr16l = (_Float16*)((char*)d_ws + 278528 + 16384);  // 16384 B

  convert_kernel<<<COUT + 16, 256, 0, stream>>>(w_reduce, w_recover, w16, wr16h, wr16l);
  fused_kernel<<<NB * (HW / 64), 256, 0, stream>>>(x, w16, wr16h, wr16l, y);
}